// Round 8
// baseline (244.961 us; speedup 1.0000x reference)
//
#include <hip/hip_runtime.h>

typedef __attribute__((ext_vector_type(8))) short short8;
typedef __attribute__((ext_vector_type(4))) float floatx4;

__device__ __forceinline__ unsigned short f2bf(float f) {
    union { float f; unsigned int u; } v; v.f = f;
    unsigned int r = (v.u + 0x7fffu + ((v.u >> 16) & 1u)) >> 16;
    return (unsigned short)r;
}

// async global -> LDS, 16B per lane. LDS dest = wave-uniform base + lane*16.
__device__ __forceinline__ void gload_lds16(const void* g, void* l) {
    __builtin_amdgcn_global_load_lds(
        (const __attribute__((address_space(1))) unsigned int*)g,
        (__attribute__((address_space(3))) unsigned int*)l, 16, 0, 0);
}

// ---------------------------------------------------------------------------
// W-prep + hbuf halo zeroing.
//   w1 -> [c4=4][tap=9][co=64][ci=32] bf16 ; w2 -> [c4=2][tap=9][co=32][ci=32]
//   + zero hbuf halo border (8 x 516 px x 8 uint4)
// grid 489 * 256 = 125,184 items exactly (73728 + 18432 + 33024).
// ---------------------------------------------------------------------------
__global__ __launch_bounds__(256) void prep_w_kernel(
    const float* __restrict__ w1, const float* __restrict__ w2,
    unsigned short* __restrict__ w1p, unsigned short* __restrict__ w2p,
    unsigned short* __restrict__ hbuf)
{
    int i = blockIdx.x * 256 + threadIdx.x;
    if (i < 73728) {
        int ci = i & 31; int t2 = i >> 5; int co = t2 & 63; int t3 = t2 >> 6;
        int tap = t3 % 9; int c4 = t3 / 9;
        float v = 0.f;
        if (co < 50) v = w1[((size_t)co * 128 + c4 * 32 + ci) * 9 + tap];
        w1p[i] = f2bf(v);
    } else if (i < 92160) {
        int j = i - 73728;
        int ci = j & 31; int t2 = j >> 5; int co = t2 & 31; int t3 = t2 >> 5;
        int tap = t3 % 9; int c4 = t3 / 9;
        int cig = c4 * 32 + ci;
        float v = 0.f;
        if (co < 18 && cig < 50) v = w2[((size_t)co * 50 + cig) * 9 + tap];
        w2p[j] = f2bf(v);
    } else {
        int k = i - 92160;                       // hbuf border
        int b = k / 4128, r = k % 4128;
        int px = r >> 3, u4 = r & 7;
        int Y, X;
        if (px < 130)      { Y = 0;        X = px; }
        else if (px < 260) { Y = 129;      X = px - 130; }
        else if (px < 388) { Y = px - 259; X = 0; }
        else               { Y = px - 387; X = 129; }
        *(uint4*)&hbuf[(((size_t)b * 130 + Y) * 130 + X) * 64 + u4 * 8] = make_uint4(0, 0, 0, 0);
    }
}

// ---------------------------------------------------------------------------
// conv1 MFMA v6 (R7-verified): fused transpose, reads ctrl NCHW f32 directly,
// bf16-converts and transpose-scatters into linear LDS [324px][32ci].
// Weights staged via gload_lds. LDS 57.6 KB -> 2 blocks/CU. grid (8,8,8).
// ---------------------------------------------------------------------------
__global__ __launch_bounds__(256, 2) void conv1_mfma(
    const float* __restrict__ ctrl, const unsigned short* __restrict__ w1p,
    const float* __restrict__ b1, const float* __restrict__ gamma,
    const float* __restrict__ beta, const float* __restrict__ mean,
    const float* __restrict__ var, unsigned short* __restrict__ h)
{
    __shared__ unsigned short in_s[324 * 32];   // [p = row*18+col][ci 0..31]
    __shared__ unsigned short w_s[2304 * 8];    // [tap][co][4q][8ci] linear
    const int tid = threadIdx.x;
    const int x0 = blockIdx.x * 16, y0 = blockIdx.y * 16, b = blockIdx.z;
    const int wid = tid >> 6, lane = tid & 63;
    const int ln = lane & 15, q = lane >> 4;

    floatx4 acc[4][4];
#pragma unroll
    for (int mt = 0; mt < 4; mt++)
#pragma unroll
        for (int nt = 0; nt < 4; nt++) acc[mt][nt] = (floatx4)(0.f);

    for (int c4 = 0; c4 < 4; c4++) {
        // stage weights: 2304 uint4, pure linear async DMA
        const unsigned short* wsrc = &w1p[(size_t)c4 * 2304 * 8];
#pragma unroll
        for (int it = 0; it < 9; it++) {
            const int cbase = it * 256 + wid * 64;
            gload_lds16(&wsrc[(size_t)(cbase + lane) * 8], &w_s[(size_t)cbase * 8]);
        }
        // stage input: fused transpose. 576 items = 18 rows x 32 ci.
#pragma unroll
        for (int r = 0; r < 3; r++) {
            const int i = r * 256 + tid;
            const bool ok = i < 576;
            const int row = i >> 5, ci = i & 31;
            const int gy = y0 - 1 + row;
            float4 wv[6];
#pragma unroll
            for (int f = 0; f < 6; f++) {
                const int xs = x0 - 4 + f * 4;
                wv[f] = make_float4(0.f, 0.f, 0.f, 0.f);
                if (ok && gy >= 0 && gy < 128 && xs >= 0 && xs < 125)
                    wv[f] = *(const float4*)&ctrl[(((size_t)b * 128 + c4 * 32 + ci) * 128 + gy) * 128 + xs];
            }
            if (ok) {
                float va[24];
#pragma unroll
                for (int f = 0; f < 6; f++) {
                    va[4 * f + 0] = wv[f].x; va[4 * f + 1] = wv[f].y;
                    va[4 * f + 2] = wv[f].z; va[4 * f + 3] = wv[f].w;
                }
                unsigned short* dst = &in_s[(row * 18) * 32 + ci];
#pragma unroll
                for (int k = 0; k < 18; k++)
                    dst[k * 32] = f2bf(va[k + 3]);
            }
        }
        __syncthreads();

#pragma unroll
        for (int tap = 0; tap < 9; tap++) {
            const int dy = tap / 3, dx = tap % 3;
            short8 a[4];
#pragma unroll
            for (int mt = 0; mt < 4; mt++)
                a[mt] = *(const short8*)&in_s[((wid * 4 + mt + dy) * 18 + ln + dx) * 32 + q * 8];
#pragma unroll
            for (int nt = 0; nt < 4; nt++) {
                short8 bf = *(const short8*)&w_s[((tap * 64 + nt * 16 + ln) * 4 + q) * 8];
#pragma unroll
                for (int mt = 0; mt < 4; mt++)
                    acc[mt][nt] = __builtin_amdgcn_mfma_f32_16x16x32_bf16(a[mt], bf, acc[mt][nt], 0, 0, 0);
            }
        }
        __syncthreads();
    }

#pragma unroll
    for (int nt = 0; nt < 4; nt++) {
        int co = nt * 16 + ln;
        bool real = co < 50;
        float sc = 0.f, mn = 0.f, bt = 0.f, bs = 0.f;
        if (real) {
            sc = gamma[co] * rsqrtf(var[co] + 1e-5f);
            mn = mean[co]; bt = beta[co]; bs = b1[co];
        }
#pragma unroll
        for (int mt = 0; mt < 4; mt++) {
            int gy = y0 + wid * 4 + mt;
#pragma unroll
            for (int r = 0; r < 4; r++) {
                int px = q * 4 + r;
                float v = 0.f;
                if (real) {
                    float tv = fmaxf(acc[mt][nt][r] + bs, 0.f);
                    v = (tv - mn) * sc + bt;
                }
                // halo'd hbuf: interior write at (gy+1, gx+1)
                h[(((size_t)b * 130 + (gy + 1)) * 130 + (x0 + px + 1)) * 64 + co] = f2bf(v);
            }
        }
    }
}

// ---------------------------------------------------------------------------
// conv2+apply FUSED. Phase 1 = R6-verified conv2 (gload_lds staging, halo'd
// hbuf, cond[b][g][cy][cx][12] written to global). Phase 2 = apply: the key
// fact is out row o, col x uses ONLY cond[o>>2][x>>2] -- taps shift the image,
// not the cond cell. So this block's 16x16 cond tile covers exactly the
// 64x64x6 output region. cond reads after __syncthreads() are L2-hits (own
// writes). img region/block = 124 KB -> tap re-reads are L1/L2-hot, and the
// apply work rides on already-resident waves (no separate dispatch ramp).
// grid (8,8,8), LDS 40 KB.
// ---------------------------------------------------------------------------
__global__ __launch_bounds__(256) void conv2_apply(
    const unsigned short* __restrict__ hT, const unsigned short* __restrict__ w2p,
    const float* __restrict__ b2, float* __restrict__ cond,
    const float* __restrict__ img, float* __restrict__ out)
{
    __shared__ unsigned short in_s[1344 * 8];
    __shared__ unsigned short w_s[1152 * 8];    // 9 taps * 32 co * 4 ci-slots
    const int tid = threadIdx.x;
    const int x0 = blockIdx.x * 16, y0 = blockIdx.y * 16, b = blockIdx.z;
    const int wid = tid >> 6, lane = tid & 63;
    const int ln = lane & 15, q = lane >> 4;

    floatx4 acc[4][2];
#pragma unroll
    for (int mt = 0; mt < 4; mt++)
#pragma unroll
        for (int nt = 0; nt < 2; nt++) acc[mt][nt] = (floatx4)(0.f);

    for (int c4 = 0; c4 < 2; c4++) {
#pragma unroll
        for (int it = 0; it < 6; it++) {
            const int cbase = it * 256 + wid * 64;
            if (cbase < 1296) {
                int j = cbase + lane; if (j > 1295) j = 1295;
                const int p = j >> 2, s = j & 3;
                const int Y = y0 + p / 18, X = x0 + p % 18;
                gload_lds16(&hT[(((size_t)b * 130 + Y) * 130 + X) * 64 + c4 * 32 + s * 8],
                            &in_s[(size_t)cbase * 8]);
            }
        }
        const unsigned short* wsrc = &w2p[(size_t)c4 * 1152 * 8];
#pragma unroll
        for (int it = 0; it < 5; it++) {
            const int cbase = it * 256 + wid * 64;
            if (cbase < 1152)
                gload_lds16(&wsrc[(size_t)(cbase + lane) * 8], &w_s[(size_t)cbase * 8]);
        }
        __syncthreads();

#pragma unroll
        for (int tap = 0; tap < 9; tap++) {
            const int dy = tap / 3, dx = tap % 3;
            short8 a[4];
#pragma unroll
            for (int mt = 0; mt < 4; mt++)
                a[mt] = *(const short8*)&in_s[(((wid * 4 + mt + dy) * 18 + ln + dx) * 4 + q) * 8];
#pragma unroll
            for (int nt = 0; nt < 2; nt++) {
                short8 bf = *(const short8*)&w_s[((tap * 32 + nt * 16 + ln) * 4 + q) * 8];
#pragma unroll
                for (int mt = 0; mt < 4; mt++)
                    acc[mt][nt] = __builtin_amdgcn_mfma_f32_16x16x32_bf16(a[mt], bf, acc[mt][nt], 0, 0, 0);
            }
        }
        __syncthreads();
    }

    // conv2 epilogue: write cond tile (L2-resident for phase 2)
#pragma unroll
    for (int nt = 0; nt < 2; nt++) {
        int co = nt * 16 + ln;
        if (co < 18) {
            float bs = b2[co];
            int gch = co / 9, k = co % 9;
            int iw = k / 3, jy = k % 3;
#pragma unroll
            for (int mt = 0; mt < 4; mt++) {
                int gy = y0 + wid * 4 + mt;
#pragma unroll
                for (int r = 0; r < 4; r++) {
                    int px = q * 4 + r;
                    cond[((((size_t)b * 2 + gch) * 128 + gy) * 128 + (x0 + px)) * 12 + jy * 4 + iw]
                        = acc[mt][nt][r] + bs;
                }
            }
        }
    }

    __syncthreads();   // drains cond stores to L2 before any thread reads

    // ---- phase 2: apply over the 64x64x6 output region of this tile ----
    {
        const int xl = tid & 15, sr = tid >> 4;
        const int x4 = x0 + xl;                  // global float4-column = cell cx
        const int xo = x4 * 4;
        const bool lok = (x4 > 0), rokx = (x4 < 127);
#pragma unroll
        for (int rr = 0; rr < 4; rr++) {
            const int o = (y0 << 2) + rr * 16 + sr;   // output row
            const int cy = o >> 2;
#pragma unroll
            for (int g = 0; g < 2; g++) {
                const float* cw = &cond[((((size_t)b * 2 + g) * 128 + cy) * 128 + x4) * 12];
                const float4 w0 = *(const float4*)&cw[0];
                const float4 w1 = *(const float4*)&cw[4];
                const float4 w2v = *(const float4*)&cw[8];

                float4 C[3][3], L[3][3], R[3][3];
#pragma unroll
                for (int jy = 0; jy < 3; jy++) {
                    const int r = o - 4 + 4 * jy;
                    const bool rk = (r >= 0) && (r < 512);
#pragma unroll
                    for (int cc = 0; cc < 3; cc++) {
                        C[jy][cc] = make_float4(0.f, 0.f, 0.f, 0.f);
                        L[jy][cc] = make_float4(0.f, 0.f, 0.f, 0.f);
                        R[jy][cc] = make_float4(0.f, 0.f, 0.f, 0.f);
                        if (rk) {
                            const float* rp = &img[((((size_t)b * 6 + g * 3 + cc) * 512) + r) * 512];
                            C[jy][cc] = *(const float4*)&rp[xo];
                            if (lok)  L[jy][cc] = *(const float4*)&rp[xo - 4];
                            if (rokx) R[jy][cc] = *(const float4*)&rp[xo + 4];
                        }
                    }
                }

                float4 a2[3];
#pragma unroll
                for (int cc = 0; cc < 3; cc++) a2[cc] = make_float4(0.f, 0.f, 0.f, 0.f);
#pragma unroll
                for (int jy = 0; jy < 3; jy++) {
                    const float4 wj = (jy == 0) ? w0 : (jy == 1) ? w1 : w2v;
#pragma unroll
                    for (int cc = 0; cc < 3; cc++) {
                        const float4 l = L[jy][cc], c = C[jy][cc], r = R[jy][cc];
                        a2[cc].x += l.x * wj.x + c.x * wj.y + r.x * wj.z;
                        a2[cc].y += l.y * wj.x + c.y * wj.y + r.y * wj.z;
                        a2[cc].z += l.z * wj.x + c.z * wj.y + r.z * wj.z;
                        a2[cc].w += l.w * wj.x + c.w * wj.y + r.w * wj.z;
                    }
                }
#pragma unroll
                for (int cc = 0; cc < 3; cc++)
                    *(float4*)&out[((((size_t)b * 6 + g * 3 + cc) * 512) + o) * 512 + xo] = a2[cc];
            }
        }
    }
}

// ---------------------------------------------------------------------------
extern "C" void kernel_launch(void* const* d_in, const int* in_sizes, int n_in,
                              void* d_out, int out_size, void* d_ws, size_t ws_size,
                              hipStream_t stream)
{
    const float* img   = (const float*)d_in[0];
    const float* ctrl  = (const float*)d_in[1];
    const float* w1    = (const float*)d_in[2];
    const float* b1    = (const float*)d_in[3];
    const float* gamma = (const float*)d_in[4];
    const float* beta  = (const float*)d_in[5];
    const float* mean  = (const float*)d_in[6];
    const float* var   = (const float*)d_in[7];
    const float* w2    = (const float*)d_in[8];
    const float* b2    = (const float*)d_in[9];
    float* out = (float*)d_out;

    char* ws = (char*)d_ws;
    unsigned short* hbuf  = (unsigned short*)ws;                        // 17,305,600 B (8*130*130*64*2)
    float*          cond  = (float*)(ws + 17305600);                    // 12,582,912 B
    unsigned short* w1p   = (unsigned short*)(ws + 29888512);           //    147,456 B
    unsigned short* w2p   = (unsigned short*)(ws + 30035968);           //     36,864 B

    prep_w_kernel<<<489, 256, 0, stream>>>(w1, w2, w1p, w2p, hbuf);
    conv1_mfma<<<dim3(8, 8, 8), 256, 0, stream>>>(ctrl, w1p, b1, gamma, beta, mean, var, hbuf);
    conv2_apply<<<dim3(8, 8, 8), 256, 0, stream>>>(hbuf, w2p, b2, cond, img, out);
}